// Round 1
// baseline (461.138 us; speedup 1.0000x reference)
//
#include <hip/hip_runtime.h>
#include <cstdint>

#define SEQn   2048
#define NHn    16
#define HDn    128
#define DMn    2048   // NH*HD
#define HIDn   2048
#define BATCHn 2
#define WINn   256
#define MROWS  (BATCHn*SEQn)  // 4096
#define WELEMS ((size_t)HIDn * DMn)

typedef short s16x8 __attribute__((ext_vector_type(8)));  // 8 bf16 (4 VGPRs)
typedef float f32x4 __attribute__((ext_vector_type(4)));  // MFMA accumulator

__device__ __forceinline__ float bf2f(ushort x) {
    union { uint u; float f; } v; v.u = ((uint)x) << 16; return v.f;
}
__device__ __forceinline__ ushort f2bf(float f) {
    union { float f; uint u; } v; v.f = f;
    uint u = v.u;
    return (ushort)((u + 0x7FFFu + ((u >> 16) & 1u)) >> 16);  // RNE
}

// Direct global->LDS DMA, 16B per lane. Dest must be wave-uniform base,
// lane's 16B lands at base + lane*16 (linear! no padding allowed).
#define GLOAD_LDS16(g, l) __builtin_amdgcn_global_load_lds(                   \
    (const __attribute__((address_space(1))) unsigned int*)(g),               \
    (__attribute__((address_space(3))) unsigned int*)(l), 16, 0, 0)

// --- ONE up-front dispatch: z=0..3 transpose {WQ,WK,WV,WO} -> WT slabs,
//     z=4: x fp32 -> bf16 (removes the mid-pipeline transpose serialization) --
__global__ __launch_bounds__(256)
void transpose_all_kernel(const float* __restrict__ WQ, const float* __restrict__ WK,
                          const float* __restrict__ WV, const float* __restrict__ WO,
                          ushort* __restrict__ WT,
                          const float* __restrict__ x, ushort* __restrict__ xb)
{
    const int tid = threadIdx.y * 32 + threadIdx.x;
    if (blockIdx.z == 4) {
        const int bid = blockIdx.y * 64 + blockIdx.x;
        const size_t base = ((size_t)bid * 256 + tid) * 8;
        const float4 a0 = *reinterpret_cast<const float4*>(x + base);
        const float4 a1 = *reinterpret_cast<const float4*>(x + base + 4);
        ushort4 o0, o1;
        o0.x = f2bf(a0.x); o0.y = f2bf(a0.y); o0.z = f2bf(a0.z); o0.w = f2bf(a0.w);
        o1.x = f2bf(a1.x); o1.y = f2bf(a1.y); o1.z = f2bf(a1.z); o1.w = f2bf(a1.w);
        *reinterpret_cast<ushort4*>(xb + base)     = o0;
        *reinterpret_cast<ushort4*>(xb + base + 4) = o1;
        return;
    }
    __shared__ ushort t[32][33];
    const float* src = (blockIdx.z == 0) ? WQ : (blockIdx.z == 1) ? WK
                     : (blockIdx.z == 2) ? WV : WO;
    ushort* dst = WT + (size_t)blockIdx.z * WELEMS;
    const int tx = threadIdx.x, ty = threadIdx.y;
    const int n  = blockIdx.x * 32 + tx;
    const int k0 = blockIdx.y * 32;
    #pragma unroll
    for (int r = ty; r < 32; r += 8)
        t[r][tx] = f2bf(src[(size_t)(k0 + r) * 2048 + n]);
    __syncthreads();
    const int k  = k0 + tx;
    const int nb = blockIdx.x * 32;
    #pragma unroll
    for (int r = ty; r < 32; r += 8)
        dst[(size_t)(nb + r) * 2048 + k] = t[tx][r];
}

// ------- single transpose+convert (fallback path only) -----------------------
__global__ __launch_bounds__(256)
void transpose_cvt_kernel(const float* __restrict__ src, ushort* __restrict__ dst)
{
    __shared__ ushort t[32][33];
    const int tx = threadIdx.x, ty = threadIdx.y;
    const int n  = blockIdx.x * 32 + tx;
    const int k0 = blockIdx.y * 32;
    #pragma unroll
    for (int r = ty; r < 32; r += 8)
        t[r][tx] = f2bf(src[(size_t)(k0 + r) * 2048 + n]);
    __syncthreads();
    const int k  = k0 + tx;
    const int nb = blockIdx.x * 32;
    #pragma unroll
    for (int r = ty; r < 32; r += 8)
        dst[(size_t)(nb + r) * 2048 + k] = t[tx][r];
}

// -------- fused QKV GEMM + fused RoPE epilogue ------------------------------
// r10: staging via global_load_lds width=16 (linear stride-64 LDS, no pad).
// m151/m193: reg-staging caps this structure at ~650 TF; gload_lds ~900 TF.
// Linear layout's 16-way ds_read conflict is benign at the 2-barrier schedule
// (m98: 1.7e7 conflicts, 874-912 TF).
template<int ABF16>
__global__ __launch_bounds__(256)
void gemm_qkv_kernel(const void* __restrict__ Araw, const ushort* __restrict__ WT,
                     const float* __restrict__ bQ, const float* __restrict__ bK,
                     const float* __restrict__ bV,
                     ushort* __restrict__ Qb, ushort* __restrict__ Kb,
                     ushort* __restrict__ Vt)
{
    // As[128][64] | Bs[128][64] linear (gload_lds dest); reused as ctile 128x136.
    __shared__ __align__(16) ushort smem[128 * 136];
    ushort* As = smem;
    ushort* Bs = smem + 128 * 64;
    const int tid = threadIdx.x;
    const int m0  = blockIdx.y * 128;
    const int n0g = blockIdx.x * 128;          // 0..6143
    const int sel = n0g >> 11;                 // 0=Q 1=K 2=V
    const int n0  = n0g & 2047;
    const ushort* BT  = WT + (size_t)sel * WELEMS;
    const float* bias = (sel == 0) ? bQ : (sel == 1) ? bK : bV;
    const int w  = tid >> 6;
    const int l  = tid & 63;
    const int wy = w >> 1, wx = w & 1;
    const int q  = l >> 4, lm = l & 15;

    f32x4 acc[4][4];
    #pragma unroll
    for (int i = 0; i < 4; ++i)
        #pragma unroll
        for (int j = 0; j < 4; ++j) acc[i][j] = (f32x4)0.0f;

    for (int kt = 0; kt < HIDn; kt += 64) {
        if (ABF16) {
            #pragma unroll
            for (int it = 0; it < 4; ++it) {
                const int v = it * 256 + tid;       // 16B-chunk index 0..1023
                const int r = v >> 3;
                const int c = (v & 7) << 3;
                const ushort* gA = (const ushort*)Araw + (size_t)(m0 + r) * HIDn + kt + c;
                const ushort* gB = BT + (size_t)(n0 + r) * HIDn + kt + c;
                GLOAD_LDS16(gA, As + (it * 256 + w * 64) * 8);
                GLOAD_LDS16(gB, Bs + (it * 256 + w * 64) * 8);
            }
        } else {
            #pragma unroll
            for (int it = 0; it < 4; ++it) {
                const int v = it * 256 + tid;
                const int r = v >> 3;
                const int c = (v & 7) << 3;
                const float* Af = (const float*)Araw + (size_t)(m0 + r) * HIDn + kt + c;
                const float4 a0 = *reinterpret_cast<const float4*>(Af);
                const float4 a1 = *reinterpret_cast<const float4*>(Af + 4);
                ushort* d = &As[v * 8];
                d[0] = f2bf(a0.x); d[1] = f2bf(a0.y); d[2] = f2bf(a0.z); d[3] = f2bf(a0.w);
                d[4] = f2bf(a1.x); d[5] = f2bf(a1.y); d[6] = f2bf(a1.z); d[7] = f2bf(a1.w);
                const ushort* gB = BT + (size_t)(n0 + r) * HIDn + kt + c;
                GLOAD_LDS16(gB, Bs + (it * 256 + w * 64) * 8);
            }
        }
        __syncthreads();
        #pragma unroll
        for (int ks = 0; ks < 2; ++ks) {
            s16x8 af[4], bfv[4];
            #pragma unroll
            for (int im = 0; im < 4; ++im)
                af[im] = *reinterpret_cast<const s16x8*>(&As[(wy * 64 + im * 16 + lm) * 64 + ks * 32 + q * 8]);
            #pragma unroll
            for (int in = 0; in < 4; ++in)
                bfv[in] = *reinterpret_cast<const s16x8*>(&Bs[(wx * 64 + in * 16 + lm) * 64 + ks * 32 + q * 8]);
            #pragma unroll
            for (int im = 0; im < 4; ++im)
                #pragma unroll
                for (int in = 0; in < 4; ++in)
                    acc[im][in] = __builtin_amdgcn_mfma_f32_16x16x32_bf16(af[im], bfv[in], acc[im][in], 0, 0, 0);
        }
        __syncthreads();
    }

    if (sel == 2) {
        #pragma unroll
        for (int in = 0; in < 4; ++in) {
            const int gcol = n0 + wx * 64 + in * 16 + lm;
            const float bv = bias[gcol];
            #pragma unroll
            for (int im = 0; im < 4; ++im) {
                const int grow0 = m0 + wy * 64 + im * 16 + q * 4;
                #pragma unroll
                for (int r = 0; r < 4; ++r) {
                    const float val = acc[im][in][r] + bv;
                    const int grow = grow0 + r;
                    const int bb = grow >> 11, s = grow & (SEQn - 1);
                    const int hh = gcol >> 7,  d = gcol & (HDn - 1);
                    Vt[(((size_t)(bb * NHn + hh)) * HDn + d) * SEQn + s] = f2bf(val);
                }
            }
        }
    } else {
        ushort* ctile = smem;                  // 128 rows x stride 136
        #pragma unroll
        for (int in = 0; in < 4; ++in) {
            const int col = wx * 64 + in * 16 + lm;
            const float bv = bias[n0 + col];
            #pragma unroll
            for (int im = 0; im < 4; ++im) {
                const int row0 = wy * 64 + im * 16 + q * 4;
                #pragma unroll
                for (int r = 0; r < 4; ++r)
                    ctile[(row0 + r) * 136 + col] = f2bf(acc[im][in][r] + bv);
            }
        }
        __syncthreads();
        ushort* dst = (sel == 0) ? Qb : Kb;
        const int d = tid & 63;
        const float invf = powf(10000.0f, -(float)d * (1.0f / 64.0f));
        for (int r = tid >> 6; r < 128; r += 4) {
            const int s = (m0 + r) & (SEQn - 1);
            const float ang = (float)s * invf;
            const float cs = cosf(ang), sn = sinf(ang);
            const float t1 = bf2f(ctile[r * 136 + d]);
            const float t2 = bf2f(ctile[r * 136 + 64 + d]);
            const size_t base = (size_t)(m0 + r) * DMn + n0 + d;
            dst[base]      = f2bf(t1 * cs - t2 * sn);
            dst[base + 64] = f2bf(t1 * sn + t2 * cs);
        }
    }
}

// ---- final GEMM: out(4096x2048 fp32) = AO(bf16) * WT^T + bias (fp32) -------
// 64(M)x128(N) tile; r10: global_load_lds staging, linear stride-64 LDS.
__global__ __launch_bounds__(256)
void gemm_out_kernel(const ushort* __restrict__ A, const ushort* __restrict__ BT,
                     const float* __restrict__ bias, float* __restrict__ C)
{
    __shared__ __align__(16) ushort As[64 * 64];
    __shared__ __align__(16) ushort Bs[128 * 64];
    const int tid = threadIdx.x;
    const int m0 = blockIdx.y * 64;
    const int n0 = blockIdx.x * 128;
    const int w  = tid >> 6;
    const int l  = tid & 63;
    const int wy = w >> 1, wx = w & 1;
    const int q  = l >> 4, lm = l & 15;

    f32x4 acc[2][4];
    #pragma unroll
    for (int i = 0; i < 2; ++i)
        #pragma unroll
        for (int j = 0; j < 4; ++j) acc[i][j] = (f32x4)0.0f;

    for (int kt = 0; kt < DMn; kt += 64) {
        #pragma unroll
        for (int it = 0; it < 2; ++it) {       // A rows 0..63
            const int v = it * 256 + tid;
            const int r = v >> 3;
            const int c = (v & 7) << 3;
            const ushort* gA = A + (size_t)(m0 + r) * DMn + kt + c;
            GLOAD_LDS16(gA, As + (it * 256 + w * 64) * 8);
        }
        #pragma unroll
        for (int it = 0; it < 4; ++it) {       // B rows 0..127
            const int v = it * 256 + tid;
            const int r = v >> 3;
            const int c = (v & 7) << 3;
            const ushort* gB = BT + (size_t)(n0 + r) * DMn + kt + c;
            GLOAD_LDS16(gB, Bs + (it * 256 + w * 64) * 8);
        }
        __syncthreads();
        #pragma unroll
        for (int ks = 0; ks < 2; ++ks) {
            s16x8 af[2], bfv[4];
            #pragma unroll
            for (int im = 0; im < 2; ++im)
                af[im] = *reinterpret_cast<const s16x8*>(&As[(wy * 32 + im * 16 + lm) * 64 + ks * 32 + q * 8]);
            #pragma unroll
            for (int in = 0; in < 4; ++in)
                bfv[in] = *reinterpret_cast<const s16x8*>(&Bs[(wx * 64 + in * 16 + lm) * 64 + ks * 32 + q * 8]);
            #pragma unroll
            for (int im = 0; im < 2; ++im)
                #pragma unroll
                for (int in = 0; in < 4; ++in)
                    acc[im][in] = __builtin_amdgcn_mfma_f32_16x16x32_bf16(af[im], bfv[in], acc[im][in], 0, 0, 0);
        }
        __syncthreads();
    }
    #pragma unroll
    for (int in = 0; in < 4; ++in) {
        const int gcol = n0 + wx * 64 + in * 16 + lm;
        const float bv = bias[gcol];
        #pragma unroll
        for (int im = 0; im < 2; ++im) {
            const int grow0 = m0 + wy * 32 + im * 16 + q * 4;
            #pragma unroll
            for (int r = 0; r < 4; ++r)
                C[(size_t)(grow0 + r) * HIDn + gcol] = acc[im][in][r] + bv;
        }
    }
}

// -------- MFMA flash attention: r4 structure + V-prefetch -------------------
// 4 waves/block, one (b,h,16-query tile) per wave. The 8 Vt frag loads are
// hoisted to chunk start (independent of softmax) so their latency overlaps
// QK^T + softmax instead of stalling the PV MFMAs. NOT loop-carried (r8
// spill lesson): +32 VGPRs live intra-iteration only, stays under the
// 128-VGPR / 4-wave-per-SIMD cliff.
__global__ __launch_bounds__(256)
void attn_mfma_kernel(const ushort* Q, const ushort* __restrict__ K,
                      const ushort* __restrict__ Vt, const float* __restrict__ kw,
                      ushort* AO)
{
    __shared__ ushort plds[4][16 * 40];   // per-wave P tile, stride 40 (2-way = free)
    const int w  = threadIdx.x >> 6;
    const int l  = threadIdx.x & 63;
    const int q  = l >> 4, lm = l & 15;
    const int gw = blockIdx.x * 4 + w;     // b(1) | h(4) | qt(7)
    const int qt = gw & 127;
    const int h  = (gw >> 7) & (NHn - 1);
    const int b  = gw >> 11;
    const int q0 = qt * 16;
    const float f = kw[h] * 0.08838834764831845f;   // kw * HD^-0.5

    s16x8 qf[4];
    const size_t qbase = ((size_t)(b * SEQn + q0 + lm)) * DMn + h * HDn;
    #pragma unroll
    for (int ks = 0; ks < 4; ++ks)
        qf[ks] = *reinterpret_cast<const s16x8*>(Q + qbase + ks * 32 + q * 8);

    f32x4 O[8];
    #pragma unroll
    for (int nt = 0; nt < 8; ++nt) O[nt] = (f32x4)0.0f;
    float m[4]    = {-1e30f, -1e30f, -1e30f, -1e30f};
    float lsum[4] = {0.f, 0.f, 0.f, 0.f};

    const int lo = q0 - WINn;
    const int c0 = lo > 0 ? (lo & ~31) : 0;
    const int nch = (q0 + 16 - c0 + 31) >> 5;

    const size_t kbh = ((size_t)(b * SEQn)) * DMn + h * HDn;
    const size_t vbh = ((size_t)(b * NHn + h)) * HDn * SEQn;

    for (int c = 0; c < nch; ++c) {
        const int kc = c0 + c * 32;
        // ---- prefetch V frags (independent of softmax) ----
        s16x8 vf[8];
        #pragma unroll
        for (int nt = 0; nt < 8; ++nt)
            vf[nt] = *reinterpret_cast<const s16x8*>(
                Vt + vbh + (size_t)(nt * 16 + lm) * SEQn + kc + q * 8);
        // ---- QK^T: two 16-key tiles, 4 chained k-MFMAs each ----
        f32x4 S[2];
        #pragma unroll
        for (int t = 0; t < 2; ++t) {
            f32x4 acc = (f32x4)0.0f;
            const size_t krow = kbh + (size_t)(kc + t * 16 + lm) * DMn;
            #pragma unroll
            for (int ks = 0; ks < 4; ++ks) {
                const s16x8 kf = *reinterpret_cast<const s16x8*>(K + krow + ks * 32 + q * 8);
                acc = __builtin_amdgcn_mfma_f32_16x16x32_bf16(qf[ks], kf, acc, 0, 0, 0);
            }
            S[t] = acc;
        }
        // ---- scale, mask, online softmax ----
        const int j0 = kc + lm, j1 = kc + 16 + lm;
        #pragma unroll
        for (int r = 0; r < 4; ++r) {
            const int i = q0 + q * 4 + r;
            float v0 = S[0][r] * f;
            float v1 = S[1][r] * f;
            if (j0 > i || j0 < i - WINn) v0 = -1e30f;
            if (j1 > i || j1 < i - WINn) v1 = -1e30f;
            float mx = fmaxf(v0, v1);
            #pragma unroll
            for (int off = 8; off > 0; off >>= 1)
                mx = fmaxf(mx, __shfl_xor(mx, off));
            const float mn = fmaxf(m[r], mx);
            const float alpha = __expf(m[r] - mn);
            m[r] = mn;
            const ushort h0 = f2bf(__expf(v0 - mn));
            const ushort h1 = f2bf(__expf(v1 - mn));
            plds[w][(q * 4 + r) * 40 + lm]      = h0;
            plds[w][(q * 4 + r) * 40 + 16 + lm] = h1;
            float ps = bf2f(h0) + bf2f(h1);
            #pragma unroll
            for (int off = 8; off > 0; off >>= 1)
                ps += __shfl_xor(ps, off);
            lsum[r] = lsum[r] * alpha + ps;
            #pragma unroll
            for (int nt = 0; nt < 8; ++nt) O[nt][r] *= alpha;
        }
        // ---- P -> A-frag via per-wave LDS round trip; P·V ----
        const s16x8 pf = *reinterpret_cast<const s16x8*>(&plds[w][lm * 40 + q * 8]);
        #pragma unroll
        for (int nt = 0; nt < 8; ++nt)
            O[nt] = __builtin_amdgcn_mfma_f32_16x16x32_bf16(pf, vf[nt], O[nt], 0, 0, 0);
    }
    #pragma unroll
    for (int r = 0; r < 4; ++r) {
        const float inv = 1.0f / lsum[r];
        const size_t orow = ((size_t)(b * SEQn + q0 + q * 4 + r)) * DMn + h * HDn;
        #pragma unroll
        for (int nt = 0; nt < 8; ++nt)
            AO[orow + nt * 16 + lm] = f2bf(O[nt][r] * inv);
    }
}

extern "C" void kernel_launch(void* const* d_in, const int* in_sizes, int n_in,
                              void* d_out, int out_size, void* d_ws, size_t ws_size,
                              hipStream_t stream)
{
    (void)in_sizes; (void)n_in; (void)out_size;
    const float* x  = (const float*)d_in[0];
    const float* WQ = (const float*)d_in[1];
    const float* bQ = (const float*)d_in[2];
    const float* WK = (const float*)d_in[3];
    const float* bK = (const float*)d_in[4];
    const float* WV = (const float*)d_in[5];
    const float* bV = (const float*)d_in[6];
    const float* WO = (const float*)d_in[7];
    const float* bO = (const float*)d_in[8];
    const float* kw = (const float*)d_in[9];
    float* out = (float*)d_out;

    // Full path: Qb/Kb/Vt (48 MB) + WT 4 slabs (32 MB) + xb (16 MB) = 96 MB.
    // Fallback (ws < 96 MB): 3 slabs, fp32-A QKV GEMM, late WO transpose.
    char* ws = (char*)d_ws;
    const size_t AELEMS = (size_t)MROWS * DMn;         // 4096*2048
    ushort* Qb = (ushort*)ws;                          // also AO (in-place)
    ushort* Kb = (ushort*)(ws + AELEMS * 2);
    ushort* Vt = (ushort*)(ws + AELEMS * 4);           // [b][h][d][s]
    ushort* WT = (ushort*)(ws + AELEMS * 6);           // up to 4 x 2048x2048 bf16
    const size_t FULL = AELEMS * 6 + WELEMS * 8 + AELEMS * 2;   // 96 MB
    const bool have_full = ws_size >= FULL;
    ushort* xb = (ushort*)(ws + AELEMS * 6 + WELEMS * 8);

    const dim3 tblk(32, 8);

    if (have_full) {
        transpose_all_kernel<<<dim3(64, 64, 5), tblk, 0, stream>>>(WQ, WK, WV, WO, WT, x, xb);
        gemm_qkv_kernel<1><<<dim3(3 * DMn / 128, MROWS / 128), 256, 0, stream>>>(
            xb, WT, bQ, bK, bV, Qb, Kb, Vt);
        attn_mfma_kernel<<<dim3(BATCHn * NHn * (SEQn / 16) / 4), 256, 0, stream>>>(Qb, Kb, Vt, kw, Qb);
        gemm_out_kernel<<<dim3(HIDn / 128, MROWS / 64), 256, 0, stream>>>(
            Qb, WT + 3 * WELEMS, bO, out);
    } else {
        transpose_all_kernel<<<dim3(64, 64, 3), tblk, 0, stream>>>(WQ, WK, WV, WO, WT, x, xb);
        gemm_qkv_kernel<0><<<dim3(3 * DMn / 128, MROWS / 128), 256, 0, stream>>>(
            x, WT, bQ, bK, bV, Qb, Kb, Vt);
        attn_mfma_kernel<<<dim3(BATCHn * NHn * (SEQn / 16) / 4), 256, 0, stream>>>(Qb, Kb, Vt, kw, Qb);
        transpose_cvt_kernel<<<dim3(64, 64), tblk, 0, stream>>>(WO, WT);
        gemm_out_kernel<<<dim3(HIDn / 128, MROWS / 64), 256, 0, stream>>>(Qb, WT, bO, out);
    }
}

// Round 2
// 403.636 us; speedup vs baseline: 1.1425x; 1.1425x over previous
//
#include <hip/hip_runtime.h>
#include <cstdint>

#define SEQn   2048
#define NHn    16
#define HDn    128
#define DMn    2048   // NH*HD
#define HIDn   2048
#define BATCHn 2
#define WINn   256
#define MROWS  (BATCHn*SEQn)  // 4096
#define WELEMS ((size_t)HIDn * DMn)

typedef short s16x8 __attribute__((ext_vector_type(8)));  // 8 bf16 (4 VGPRs)
typedef float f32x4 __attribute__((ext_vector_type(4)));  // MFMA accumulator

__device__ __forceinline__ float bf2f(ushort x) {
    union { uint u; float f; } v; v.u = ((uint)x) << 16; return v.f;
}
__device__ __forceinline__ ushort f2bf(float f) {
    union { float f; uint u; } v; v.f = f;
    uint u = v.u;
    return (ushort)((u + 0x7FFFu + ((u >> 16) & 1u)) >> 16);  // RNE
}

// Direct global->LDS DMA, 16B per lane. Dest must be wave-uniform base,
// lane's 16B lands at base + lane*16 (linear! no padding allowed).
#define GLOAD_LDS16(g, l) __builtin_amdgcn_global_load_lds(                   \
    (const __attribute__((address_space(1))) unsigned int*)(g),               \
    (__attribute__((address_space(3))) unsigned int*)(l), 16, 0, 0)

// --- ONE up-front dispatch: z=0..3 transpose {WQ,WK,WV,WO} -> WT slabs,
//     z=4: x fp32 -> bf16 (removes the mid-pipeline transpose serialization) --
__global__ __launch_bounds__(256)
void transpose_all_kernel(const float* __restrict__ WQ, const float* __restrict__ WK,
                          const float* __restrict__ WV, const float* __restrict__ WO,
                          ushort* __restrict__ WT,
                          const float* __restrict__ x, ushort* __restrict__ xb)
{
    const int tid = threadIdx.y * 32 + threadIdx.x;
    if (blockIdx.z == 4) {
        const int bid = blockIdx.y * 64 + blockIdx.x;
        const size_t base = ((size_t)bid * 256 + tid) * 8;
        const float4 a0 = *reinterpret_cast<const float4*>(x + base);
        const float4 a1 = *reinterpret_cast<const float4*>(x + base + 4);
        ushort4 o0, o1;
        o0.x = f2bf(a0.x); o0.y = f2bf(a0.y); o0.z = f2bf(a0.z); o0.w = f2bf(a0.w);
        o1.x = f2bf(a1.x); o1.y = f2bf(a1.y); o1.z = f2bf(a1.z); o1.w = f2bf(a1.w);
        *reinterpret_cast<ushort4*>(xb + base)     = o0;
        *reinterpret_cast<ushort4*>(xb + base + 4) = o1;
        return;
    }
    __shared__ ushort t[32][33];
    const float* src = (blockIdx.z == 0) ? WQ : (blockIdx.z == 1) ? WK
                     : (blockIdx.z == 2) ? WV : WO;
    ushort* dst = WT + (size_t)blockIdx.z * WELEMS;
    const int tx = threadIdx.x, ty = threadIdx.y;
    const int n  = blockIdx.x * 32 + tx;
    const int k0 = blockIdx.y * 32;
    #pragma unroll
    for (int r = ty; r < 32; r += 8)
        t[r][tx] = f2bf(src[(size_t)(k0 + r) * 2048 + n]);
    __syncthreads();
    const int k  = k0 + tx;
    const int nb = blockIdx.x * 32;
    #pragma unroll
    for (int r = ty; r < 32; r += 8)
        dst[(size_t)(nb + r) * 2048 + k] = t[tx][r];
}

// ------- single transpose+convert (fallback path only) -----------------------
__global__ __launch_bounds__(256)
void transpose_cvt_kernel(const float* __restrict__ src, ushort* __restrict__ dst)
{
    __shared__ ushort t[32][33];
    const int tx = threadIdx.x, ty = threadIdx.y;
    const int n  = blockIdx.x * 32 + tx;
    const int k0 = blockIdx.y * 32;
    #pragma unroll
    for (int r = ty; r < 32; r += 8)
        t[r][tx] = f2bf(src[(size_t)(k0 + r) * 2048 + n]);
    __syncthreads();
    const int k  = k0 + tx;
    const int nb = blockIdx.x * 32;
    #pragma unroll
    for (int r = ty; r < 32; r += 8)
        dst[(size_t)(nb + r) * 2048 + k] = t[tx][r];
}

// -------- fused QKV GEMM + fused RoPE epilogue ------------------------------
// r11: gload_lds staging + BOTH-SIDES XOR swizzle (rule #21 / m173+m201):
//   - LDS dest stays linear (gload_lds requirement),
//   - global SOURCE chunk pre-swizzled: c ^= (row & 7)   (involution),
//   - ds_read chunk swizzled the same way: chunk = (ks*4+q) ^ (lm&7).
// Kills the 16-way ds_read_b128 bank conflict of the linear layout
// (r1 measured 3.78e7 conflict cycles — m201's exact signature).
// RoPE epilogue: libm cosf/sinf/powf -> __sincosf/exp2f (was ~half the
// main-loop VALU cost; bf16 output tolerates ~1e-4 phase error).
template<int ABF16>
__global__ __launch_bounds__(256)
void gemm_qkv_kernel(const void* __restrict__ Araw, const ushort* __restrict__ WT,
                     const float* __restrict__ bQ, const float* __restrict__ bK,
                     const float* __restrict__ bV,
                     ushort* __restrict__ Qb, ushort* __restrict__ Kb,
                     ushort* __restrict__ Vt)
{
    // As[128][64] | Bs[128][64] linear (gload_lds dest); reused as ctile 128x136.
    __shared__ __align__(16) ushort smem[128 * 136];
    ushort* As = smem;
    ushort* Bs = smem + 128 * 64;
    const int tid = threadIdx.x;
    const int m0  = blockIdx.y * 128;
    const int n0g = blockIdx.x * 128;          // 0..6143
    const int sel = n0g >> 11;                 // 0=Q 1=K 2=V
    const int n0  = n0g & 2047;
    const ushort* BT  = WT + (size_t)sel * WELEMS;
    const float* bias = (sel == 0) ? bQ : (sel == 1) ? bK : bV;
    const int w  = tid >> 6;
    const int l  = tid & 63;
    const int wy = w >> 1, wx = w & 1;
    const int q  = l >> 4, lm = l & 15;
    const int sw = lm & 7;                     // read-side XOR (row & 7 == lm & 7)

    f32x4 acc[4][4];
    #pragma unroll
    for (int i = 0; i < 4; ++i)
        #pragma unroll
        for (int j = 0; j < 4; ++j) acc[i][j] = (f32x4)0.0f;

    for (int kt = 0; kt < HIDn; kt += 64) {
        if (ABF16) {
            #pragma unroll
            for (int it = 0; it < 4; ++it) {
                const int v = it * 256 + tid;       // 16B-chunk index 0..1023
                const int r = v >> 3;
                const int cs = ((v & 7) ^ (r & 7)) << 3;   // pre-swizzled source col
                const ushort* gA = (const ushort*)Araw + (size_t)(m0 + r) * HIDn + kt + cs;
                const ushort* gB = BT + (size_t)(n0 + r) * HIDn + kt + cs;
                GLOAD_LDS16(gA, As + (it * 256 + w * 64) * 8);
                GLOAD_LDS16(gB, Bs + (it * 256 + w * 64) * 8);
            }
        } else {
            #pragma unroll
            for (int it = 0; it < 4; ++it) {
                const int v = it * 256 + tid;
                const int r = v >> 3;
                const int c = (v & 7) << 3;
                const float* Af = (const float*)Araw + (size_t)(m0 + r) * HIDn + kt + c;
                const float4 a0 = *reinterpret_cast<const float4*>(Af);
                const float4 a1 = *reinterpret_cast<const float4*>(Af + 4);
                ushort* d = &As[(size_t)(v ^ (r & 7)) * 8];   // swizzled dest chunk
                d[0] = f2bf(a0.x); d[1] = f2bf(a0.y); d[2] = f2bf(a0.z); d[3] = f2bf(a0.w);
                d[4] = f2bf(a1.x); d[5] = f2bf(a1.y); d[6] = f2bf(a1.z); d[7] = f2bf(a1.w);
                const int cs = ((v & 7) ^ (r & 7)) << 3;
                const ushort* gB = BT + (size_t)(n0 + r) * HIDn + kt + cs;
                GLOAD_LDS16(gB, Bs + (it * 256 + w * 64) * 8);
            }
        }
        __syncthreads();
        #pragma unroll
        for (int ks = 0; ks < 2; ++ks) {
            s16x8 af[4], bfv[4];
            #pragma unroll
            for (int im = 0; im < 4; ++im) {
                const int arow = wy * 64 + im * 16 + lm;
                af[im] = *reinterpret_cast<const s16x8*>(
                    &As[arow * 64 + (((ks * 4 + q) ^ sw) << 3)]);
            }
            #pragma unroll
            for (int in = 0; in < 4; ++in) {
                const int brow = wx * 64 + in * 16 + lm;
                bfv[in] = *reinterpret_cast<const s16x8*>(
                    &Bs[brow * 64 + (((ks * 4 + q) ^ sw) << 3)]);
            }
            #pragma unroll
            for (int im = 0; im < 4; ++im)
                #pragma unroll
                for (int in = 0; in < 4; ++in)
                    acc[im][in] = __builtin_amdgcn_mfma_f32_16x16x32_bf16(af[im], bfv[in], acc[im][in], 0, 0, 0);
        }
        __syncthreads();
    }

    if (sel == 2) {
        #pragma unroll
        for (int in = 0; in < 4; ++in) {
            const int gcol = n0 + wx * 64 + in * 16 + lm;
            const float bv = bias[gcol];
            #pragma unroll
            for (int im = 0; im < 4; ++im) {
                const int grow0 = m0 + wy * 64 + im * 16 + q * 4;
                #pragma unroll
                for (int r = 0; r < 4; ++r) {
                    const float val = acc[im][in][r] + bv;
                    const int grow = grow0 + r;
                    const int bb = grow >> 11, s = grow & (SEQn - 1);
                    const int hh = gcol >> 7,  d = gcol & (HDn - 1);
                    Vt[(((size_t)(bb * NHn + hh)) * HDn + d) * SEQn + s] = f2bf(val);
                }
            }
        }
    } else {
        ushort* ctile = smem;                  // 128 rows x stride 136
        #pragma unroll
        for (int in = 0; in < 4; ++in) {
            const int col = wx * 64 + in * 16 + lm;
            const float bv = bias[n0 + col];
            #pragma unroll
            for (int im = 0; im < 4; ++im) {
                const int row0 = wy * 64 + im * 16 + q * 4;
                #pragma unroll
                for (int r = 0; r < 4; ++r)
                    ctile[(row0 + r) * 136 + col] = f2bf(acc[im][in][r] + bv);
            }
        }
        __syncthreads();
        ushort* dst = (sel == 0) ? Qb : Kb;
        const int d = tid & 63;
        const float invf = exp2f(-(float)d * 0.20762050593046f);  // 10000^(-d/64)
        for (int r = tid >> 6; r < 128; r += 4) {
            const int s = (m0 + r) & (SEQn - 1);
            const float ang = (float)s * invf;
            float sn, cs;
            __sincosf(ang, &sn, &cs);
            const float t1 = bf2f(ctile[r * 136 + d]);
            const float t2 = bf2f(ctile[r * 136 + 64 + d]);
            const size_t base = (size_t)(m0 + r) * DMn + n0 + d;
            dst[base]      = f2bf(t1 * cs - t2 * sn);
            dst[base + 64] = f2bf(t1 * sn + t2 * cs);
        }
    }
}

// ---- final GEMM: out(4096x2048 fp32) = AO(bf16) * WT^T + bias (fp32) -------
// 64(M)x128(N) tile; gload_lds staging + both-sides XOR swizzle (see qkv).
__global__ __launch_bounds__(256)
void gemm_out_kernel(const ushort* __restrict__ A, const ushort* __restrict__ BT,
                     const float* __restrict__ bias, float* __restrict__ C)
{
    __shared__ __align__(16) ushort As[64 * 64];
    __shared__ __align__(16) ushort Bs[128 * 64];
    const int tid = threadIdx.x;
    const int m0 = blockIdx.y * 64;
    const int n0 = blockIdx.x * 128;
    const int w  = tid >> 6;
    const int l  = tid & 63;
    const int wy = w >> 1, wx = w & 1;
    const int q  = l >> 4, lm = l & 15;
    const int sw = lm & 7;

    f32x4 acc[2][4];
    #pragma unroll
    for (int i = 0; i < 2; ++i)
        #pragma unroll
        for (int j = 0; j < 4; ++j) acc[i][j] = (f32x4)0.0f;

    for (int kt = 0; kt < DMn; kt += 64) {
        #pragma unroll
        for (int it = 0; it < 2; ++it) {       // A rows 0..63
            const int v = it * 256 + tid;
            const int r = v >> 3;
            const int cs = ((v & 7) ^ (r & 7)) << 3;
            const ushort* gA = A + (size_t)(m0 + r) * DMn + kt + cs;
            GLOAD_LDS16(gA, As + (it * 256 + w * 64) * 8);
        }
        #pragma unroll
        for (int it = 0; it < 4; ++it) {       // B rows 0..127
            const int v = it * 256 + tid;
            const int r = v >> 3;
            const int cs = ((v & 7) ^ (r & 7)) << 3;
            const ushort* gB = BT + (size_t)(n0 + r) * DMn + kt + cs;
            GLOAD_LDS16(gB, Bs + (it * 256 + w * 64) * 8);
        }
        __syncthreads();
        #pragma unroll
        for (int ks = 0; ks < 2; ++ks) {
            s16x8 af[2], bfv[4];
            #pragma unroll
            for (int im = 0; im < 2; ++im) {
                const int arow = wy * 32 + im * 16 + lm;
                af[im] = *reinterpret_cast<const s16x8*>(
                    &As[arow * 64 + (((ks * 4 + q) ^ sw) << 3)]);
            }
            #pragma unroll
            for (int in = 0; in < 4; ++in) {
                const int brow = wx * 64 + in * 16 + lm;
                bfv[in] = *reinterpret_cast<const s16x8*>(
                    &Bs[brow * 64 + (((ks * 4 + q) ^ sw) << 3)]);
            }
            #pragma unroll
            for (int im = 0; im < 2; ++im)
                #pragma unroll
                for (int in = 0; in < 4; ++in)
                    acc[im][in] = __builtin_amdgcn_mfma_f32_16x16x32_bf16(af[im], bfv[in], acc[im][in], 0, 0, 0);
        }
        __syncthreads();
    }
    #pragma unroll
    for (int in = 0; in < 4; ++in) {
        const int gcol = n0 + wx * 64 + in * 16 + lm;
        const float bv = bias[gcol];
        #pragma unroll
        for (int im = 0; im < 2; ++im) {
            const int grow0 = m0 + wy * 32 + im * 16 + q * 4;
            #pragma unroll
            for (int r = 0; r < 4; ++r)
                C[(size_t)(grow0 + r) * HIDn + gcol] = acc[im][in][r] + bv;
        }
    }
}

// -------- MFMA flash attention: r4 structure + V-prefetch -------------------
// 4 waves/block, one (b,h,16-query tile) per wave. The 8 Vt frag loads are
// hoisted to chunk start (independent of softmax) so their latency overlaps
// QK^T + softmax instead of stalling the PV MFMAs. NOT loop-carried (r8
// spill lesson): +32 VGPRs live intra-iteration only, stays under the
// 128-VGPR / 4-wave-per-SIMD cliff.
__global__ __launch_bounds__(256)
void attn_mfma_kernel(const ushort* Q, const ushort* __restrict__ K,
                      const ushort* __restrict__ Vt, const float* __restrict__ kw,
                      ushort* AO)
{
    __shared__ ushort plds[4][16 * 40];   // per-wave P tile, stride 40 (2-way = free)
    const int w  = threadIdx.x >> 6;
    const int l  = threadIdx.x & 63;
    const int q  = l >> 4, lm = l & 15;
    const int gw = blockIdx.x * 4 + w;     // b(1) | h(4) | qt(7)
    const int qt = gw & 127;
    const int h  = (gw >> 7) & (NHn - 1);
    const int b  = gw >> 11;
    const int q0 = qt * 16;
    const float f = kw[h] * 0.08838834764831845f;   // kw * HD^-0.5

    s16x8 qf[4];
    const size_t qbase = ((size_t)(b * SEQn + q0 + lm)) * DMn + h * HDn;
    #pragma unroll
    for (int ks = 0; ks < 4; ++ks)
        qf[ks] = *reinterpret_cast<const s16x8*>(Q + qbase + ks * 32 + q * 8);

    f32x4 O[8];
    #pragma unroll
    for (int nt = 0; nt < 8; ++nt) O[nt] = (f32x4)0.0f;
    float m[4]    = {-1e30f, -1e30f, -1e30f, -1e30f};
    float lsum[4] = {0.f, 0.f, 0.f, 0.f};

    const int lo = q0 - WINn;
    const int c0 = lo > 0 ? (lo & ~31) : 0;
    const int nch = (q0 + 16 - c0 + 31) >> 5;

    const size_t kbh = ((size_t)(b * SEQn)) * DMn + h * HDn;
    const size_t vbh = ((size_t)(b * NHn + h)) * HDn * SEQn;

    for (int c = 0; c < nch; ++c) {
        const int kc = c0 + c * 32;
        // ---- prefetch V frags (independent of softmax) ----
        s16x8 vf[8];
        #pragma unroll
        for (int nt = 0; nt < 8; ++nt)
            vf[nt] = *reinterpret_cast<const s16x8*>(
                Vt + vbh + (size_t)(nt * 16 + lm) * SEQn + kc + q * 8);
        // ---- QK^T: two 16-key tiles, 4 chained k-MFMAs each ----
        f32x4 S[2];
        #pragma unroll
        for (int t = 0; t < 2; ++t) {
            f32x4 acc = (f32x4)0.0f;
            const size_t krow = kbh + (size_t)(kc + t * 16 + lm) * DMn;
            #pragma unroll
            for (int ks = 0; ks < 4; ++ks) {
                const s16x8 kf = *reinterpret_cast<const s16x8*>(K + krow + ks * 32 + q * 8);
                acc = __builtin_amdgcn_mfma_f32_16x16x32_bf16(qf[ks], kf, acc, 0, 0, 0);
            }
            S[t] = acc;
        }
        // ---- scale, mask, online softmax ----
        const int j0 = kc + lm, j1 = kc + 16 + lm;
        #pragma unroll
        for (int r = 0; r < 4; ++r) {
            const int i = q0 + q * 4 + r;
            float v0 = S[0][r] * f;
            float v1 = S[1][r] * f;
            if (j0 > i || j0 < i - WINn) v0 = -1e30f;
            if (j1 > i || j1 < i - WINn) v1 = -1e30f;
            float mx = fmaxf(v0, v1);
            #pragma unroll
            for (int off = 8; off > 0; off >>= 1)
                mx = fmaxf(mx, __shfl_xor(mx, off));
            const float mn = fmaxf(m[r], mx);
            const float alpha = __expf(m[r] - mn);
            m[r] = mn;
            const ushort h0 = f2bf(__expf(v0 - mn));
            const ushort h1 = f2bf(__expf(v1 - mn));
            plds[w][(q * 4 + r) * 40 + lm]      = h0;
            plds[w][(q * 4 + r) * 40 + 16 + lm] = h1;
            float ps = bf2f(h0) + bf2f(h1);
            #pragma unroll
            for (int off = 8; off > 0; off >>= 1)
                ps += __shfl_xor(ps, off);
            lsum[r] = lsum[r] * alpha + ps;
            #pragma unroll
            for (int nt = 0; nt < 8; ++nt) O[nt][r] *= alpha;
        }
        // ---- P -> A-frag via per-wave LDS round trip; P·V ----
        const s16x8 pf = *reinterpret_cast<const s16x8*>(&plds[w][lm * 40 + q * 8]);
        #pragma unroll
        for (int nt = 0; nt < 8; ++nt)
            O[nt] = __builtin_amdgcn_mfma_f32_16x16x32_bf16(pf, vf[nt], O[nt], 0, 0, 0);
    }
    #pragma unroll
    for (int r = 0; r < 4; ++r) {
        const float inv = 1.0f / lsum[r];
        const size_t orow = ((size_t)(b * SEQn + q0 + q * 4 + r)) * DMn + h * HDn;
        #pragma unroll
        for (int nt = 0; nt < 8; ++nt)
            AO[orow + nt * 16 + lm] = f2bf(O[nt][r] * inv);
    }
}

extern "C" void kernel_launch(void* const* d_in, const int* in_sizes, int n_in,
                              void* d_out, int out_size, void* d_ws, size_t ws_size,
                              hipStream_t stream)
{
    (void)in_sizes; (void)n_in; (void)out_size;
    const float* x  = (const float*)d_in[0];
    const float* WQ = (const float*)d_in[1];
    const float* bQ = (const float*)d_in[2];
    const float* WK = (const float*)d_in[3];
    const float* bK = (const float*)d_in[4];
    const float* WV = (const float*)d_in[5];
    const float* bV = (const float*)d_in[6];
    const float* WO = (const float*)d_in[7];
    const float* bO = (const float*)d_in[8];
    const float* kw = (const float*)d_in[9];
    float* out = (float*)d_out;

    // Full path: Qb/Kb/Vt (48 MB) + WT 4 slabs (32 MB) + xb (16 MB) = 96 MB.
    // Fallback (ws < 96 MB): 3 slabs, fp32-A QKV GEMM, late WO transpose.
    char* ws = (char*)d_ws;
    const size_t AELEMS = (size_t)MROWS * DMn;         // 4096*2048
    ushort* Qb = (ushort*)ws;                          // also AO (in-place)
    ushort* Kb = (ushort*)(ws + AELEMS * 2);
    ushort* Vt = (ushort*)(ws + AELEMS * 4);           // [b][h][d][s]
    ushort* WT = (ushort*)(ws + AELEMS * 6);           // up to 4 x 2048x2048 bf16
    const size_t FULL = AELEMS * 6 + WELEMS * 8 + AELEMS * 2;   // 96 MB
    const bool have_full = ws_size >= FULL;
    ushort* xb = (ushort*)(ws + AELEMS * 6 + WELEMS * 8);

    const dim3 tblk(32, 8);

    if (have_full) {
        transpose_all_kernel<<<dim3(64, 64, 5), tblk, 0, stream>>>(WQ, WK, WV, WO, WT, x, xb);
        gemm_qkv_kernel<1><<<dim3(3 * DMn / 128, MROWS / 128), 256, 0, stream>>>(
            xb, WT, bQ, bK, bV, Qb, Kb, Vt);
        attn_mfma_kernel<<<dim3(BATCHn * NHn * (SEQn / 16) / 4), 256, 0, stream>>>(Qb, Kb, Vt, kw, Qb);
        gemm_out_kernel<<<dim3(HIDn / 128, MROWS / 64), 256, 0, stream>>>(
            Qb, WT + 3 * WELEMS, bO, out);
    } else {
        transpose_all_kernel<<<dim3(64, 64, 3), tblk, 0, stream>>>(WQ, WK, WV, WO, WT, x, xb);
        gemm_qkv_kernel<0><<<dim3(3 * DMn / 128, MROWS / 128), 256, 0, stream>>>(
            x, WT, bQ, bK, bV, Qb, Kb, Vt);
        attn_mfma_kernel<<<dim3(BATCHn * NHn * (SEQn / 16) / 4), 256, 0, stream>>>(Qb, Kb, Vt, kw, Qb);
        transpose_cvt_kernel<<<dim3(64, 64), tblk, 0, stream>>>(WO, WT);
        gemm_out_kernel<<<dim3(HIDn / 128, MROWS / 64), 256, 0, stream>>>(Qb, WT, bO, out);
    }
}

// Round 3
// 374.450 us; speedup vs baseline: 1.2315x; 1.0779x over previous
//
#include <hip/hip_runtime.h>
#include <cstdint>

#define SEQn   2048
#define NHn    16
#define HDn    128
#define DMn    2048   // NH*HD
#define HIDn   2048
#define BATCHn 2
#define WINn   256
#define MROWS  (BATCHn*SEQn)  // 4096
#define WELEMS ((size_t)HIDn * DMn)

typedef short s16x8 __attribute__((ext_vector_type(8)));  // 8 bf16 (4 VGPRs)
typedef float f32x4 __attribute__((ext_vector_type(4)));  // MFMA accumulator

__device__ __forceinline__ float bf2f(ushort x) {
    union { uint u; float f; } v; v.u = ((uint)x) << 16; return v.f;
}
__device__ __forceinline__ ushort f2bf(float f) {
    union { float f; uint u; } v; v.f = f;
    uint u = v.u;
    return (ushort)((u + 0x7FFFu + ((u >> 16) & 1u)) >> 16);  // RNE
}

// Direct global->LDS DMA, 16B per lane. Dest must be wave-uniform base,
// lane's 16B lands at base + lane*16 (linear! no padding allowed).
#define GLOAD_LDS16(g, l) __builtin_amdgcn_global_load_lds(                   \
    (const __attribute__((address_space(1))) unsigned int*)(g),               \
    (__attribute__((address_space(3))) unsigned int*)(l), 16, 0, 0)

// Compiler fence: no memory op or instruction crosses (rule #18 discipline —
// raw s_barrier is NOT a compiler fence; C++ ds_reads would hoist past it).
#define FENCE() do { asm volatile("" ::: "memory");                           \
                     __builtin_amdgcn_sched_barrier(0); } while (0)

// --- ONE up-front dispatch: z=0..3 transpose {WQ,WK,WV,WO} -> WT slabs,
//     z=4: x fp32 -> bf16 (removes the mid-pipeline transpose serialization) --
__global__ __launch_bounds__(256)
void transpose_all_kernel(const float* __restrict__ WQ, const float* __restrict__ WK,
                          const float* __restrict__ WV, const float* __restrict__ WO,
                          ushort* __restrict__ WT,
                          const float* __restrict__ x, ushort* __restrict__ xb)
{
    const int tid = threadIdx.y * 32 + threadIdx.x;
    if (blockIdx.z == 4) {
        const int bid = blockIdx.y * 64 + blockIdx.x;
        const size_t base = ((size_t)bid * 256 + tid) * 8;
        const float4 a0 = *reinterpret_cast<const float4*>(x + base);
        const float4 a1 = *reinterpret_cast<const float4*>(x + base + 4);
        ushort4 o0, o1;
        o0.x = f2bf(a0.x); o0.y = f2bf(a0.y); o0.z = f2bf(a0.z); o0.w = f2bf(a0.w);
        o1.x = f2bf(a1.x); o1.y = f2bf(a1.y); o1.z = f2bf(a1.z); o1.w = f2bf(a1.w);
        *reinterpret_cast<ushort4*>(xb + base)     = o0;
        *reinterpret_cast<ushort4*>(xb + base + 4) = o1;
        return;
    }
    __shared__ ushort t[32][33];
    const float* src = (blockIdx.z == 0) ? WQ : (blockIdx.z == 1) ? WK
                     : (blockIdx.z == 2) ? WV : WO;
    ushort* dst = WT + (size_t)blockIdx.z * WELEMS;
    const int tx = threadIdx.x, ty = threadIdx.y;
    const int n  = blockIdx.x * 32 + tx;
    const int k0 = blockIdx.y * 32;
    #pragma unroll
    for (int r = ty; r < 32; r += 8)
        t[r][tx] = f2bf(src[(size_t)(k0 + r) * 2048 + n]);
    __syncthreads();
    const int k  = k0 + tx;
    const int nb = blockIdx.x * 32;
    #pragma unroll
    for (int r = ty; r < 32; r += 8)
        dst[(size_t)(nb + r) * 2048 + k] = t[tx][r];
}

// ------- single transpose+convert (fallback path only) -----------------------
__global__ __launch_bounds__(256)
void transpose_cvt_kernel(const float* __restrict__ src, ushort* __restrict__ dst)
{
    __shared__ ushort t[32][33];
    const int tx = threadIdx.x, ty = threadIdx.y;
    const int n  = blockIdx.x * 32 + tx;
    const int k0 = blockIdx.y * 32;
    #pragma unroll
    for (int r = ty; r < 32; r += 8)
        t[r][tx] = f2bf(src[(size_t)(k0 + r) * 2048 + n]);
    __syncthreads();
    const int k  = k0 + tx;
    const int nb = blockIdx.x * 32;
    #pragma unroll
    for (int r = ty; r < 32; r += 8)
        dst[(size_t)(nb + r) * 2048 + k] = t[tx][r];
}

// -------- fused QKV GEMM + fused RoPE epilogue ------------------------------
// r12: T4 counted-vmcnt double-buffer pipeline (AITER pattern, m218):
//   stage tile t+1 -> vmcnt(8) [t+1's loads stay IN FLIGHT across barriers]
//   -> barrier -> ds_read+MFMA(tile t) -> barrier.  Never vmcnt(0) in loop.
// LDS 64KB (2 slots x (A 16K + B 16K)) -> 2 blocks/CU. Raw s_barrier + FENCE
// (rule #18: raw barrier is not a compiler fence). Both-sides XOR swizzle
// kept (r2: conflicts 3.78e7 -> 0). V epilogue: LDS-transpose + coalesced
// 16B stores (was 64x scattered 2B stores/thread).
template<int ABF16>
__global__ __launch_bounds__(256)
void gemm_qkv_kernel(const void* __restrict__ Araw, const ushort* __restrict__ WT,
                     const float* __restrict__ bQ, const float* __restrict__ bK,
                     const float* __restrict__ bV,
                     ushort* __restrict__ Qb, ushort* __restrict__ Kb,
                     ushort* __restrict__ Vt)
{
    // slot s: As = smem + s*16384 (128x64), Bs = +8192. ctile aliases slot 0.
    __shared__ __align__(16) ushort smem[32768];   // 64 KB
    const int tid = threadIdx.x;
    const int m0  = blockIdx.y * 128;
    const int n0g = blockIdx.x * 128;          // 0..6143
    const int sel = n0g >> 11;                 // 0=Q 1=K 2=V
    const int n0  = n0g & 2047;
    const ushort* BT  = WT + (size_t)sel * WELEMS;
    const float* bias = (sel == 0) ? bQ : (sel == 1) ? bK : bV;
    const int w  = tid >> 6;
    const int l  = tid & 63;
    const int wy = w >> 1, wx = w & 1;
    const int q  = l >> 4, lm = l & 15;
    const int sw = lm & 7;                     // read-side XOR (row & 7 == lm & 7)

    f32x4 acc[4][4];
    #pragma unroll
    for (int i = 0; i < 4; ++i)
        #pragma unroll
        for (int j = 0; j < 4; ++j) acc[i][j] = (f32x4)0.0f;

    auto stage = [&](int slot, int kt) {
        ushort* AsS = smem + slot * 16384;
        ushort* BsS = AsS + 8192;
        if (ABF16) {
            #pragma unroll
            for (int it = 0; it < 4; ++it) {
                const int v = it * 256 + tid;       // 16B-chunk index 0..1023
                const int r = v >> 3;
                const int cs = ((v & 7) ^ (r & 7)) << 3;   // pre-swizzled src col
                const ushort* gA = (const ushort*)Araw + (size_t)(m0 + r) * HIDn + kt + cs;
                const ushort* gB = BT + (size_t)(n0 + r) * HIDn + kt + cs;
                GLOAD_LDS16(gA, AsS + (it * 256 + w * 64) * 8);
                GLOAD_LDS16(gB, BsS + (it * 256 + w * 64) * 8);
            }
        } else {
            #pragma unroll
            for (int it = 0; it < 4; ++it) {
                const int v = it * 256 + tid;
                const int r = v >> 3;
                const int c = (v & 7) << 3;
                const float* Af = (const float*)Araw + (size_t)(m0 + r) * HIDn + kt + c;
                const float4 a0 = *reinterpret_cast<const float4*>(Af);
                const float4 a1 = *reinterpret_cast<const float4*>(Af + 4);
                ushort* d = &AsS[(size_t)(v ^ (r & 7)) * 8];   // swizzled dest chunk
                d[0] = f2bf(a0.x); d[1] = f2bf(a0.y); d[2] = f2bf(a0.z); d[3] = f2bf(a0.w);
                d[4] = f2bf(a1.x); d[5] = f2bf(a1.y); d[6] = f2bf(a1.z); d[7] = f2bf(a1.w);
                const int cs = ((v & 7) ^ (r & 7)) << 3;
                const ushort* gB = BT + (size_t)(n0 + r) * HIDn + kt + cs;
                GLOAD_LDS16(gB, BsS + (it * 256 + w * 64) * 8);
            }
        }
    };

    auto compute = [&](int slot) {
        const ushort* AsS = smem + slot * 16384;
        const ushort* BsS = AsS + 8192;
        #pragma unroll
        for (int ks = 0; ks < 2; ++ks) {
            s16x8 af[4], bfv[4];
            #pragma unroll
            for (int im = 0; im < 4; ++im) {
                const int arow = wy * 64 + im * 16 + lm;
                af[im] = *reinterpret_cast<const s16x8*>(
                    &AsS[arow * 64 + (((ks * 4 + q) ^ sw) << 3)]);
            }
            #pragma unroll
            for (int in = 0; in < 4; ++in) {
                const int brow = wx * 64 + in * 16 + lm;
                bfv[in] = *reinterpret_cast<const s16x8*>(
                    &BsS[brow * 64 + (((ks * 4 + q) ^ sw) << 3)]);
            }
            __builtin_amdgcn_s_setprio(1);
            #pragma unroll
            for (int im = 0; im < 4; ++im)
                #pragma unroll
                for (int in = 0; in < 4; ++in)
                    acc[im][in] = __builtin_amdgcn_mfma_f32_16x16x32_bf16(af[im], bfv[in], acc[im][in], 0, 0, 0);
            __builtin_amdgcn_s_setprio(0);
        }
    };

    const int NT = HIDn / 64;   // 32
    stage(0, 0);
    int cur = 0;
    for (int t = 0; t < NT - 1; ++t) {
        stage(cur ^ 1, (t + 1) * 64);
        if (ABF16) asm volatile("s_waitcnt vmcnt(8)" ::: "memory");
        else       asm volatile("s_waitcnt vmcnt(4)" ::: "memory");
        __builtin_amdgcn_s_barrier();
        FENCE();
        compute(cur);
        FENCE();
        if (!ABF16) asm volatile("s_waitcnt lgkmcnt(0)" ::: "memory");
        __builtin_amdgcn_s_barrier();
        FENCE();
        cur ^= 1;
    }
    asm volatile("s_waitcnt vmcnt(0)" ::: "memory");
    __builtin_amdgcn_s_barrier();
    FENCE();
    compute(cur);
    __syncthreads();   // full fence before ctile aliases As/Bs

    if (sel == 2) {
        // LDS-transposed coalesced V store: ctile[d][s], stride 136 (2-way free).
        ushort* ctile = smem;
        #pragma unroll
        for (int in = 0; in < 4; ++in) {
            const int col = wx * 64 + in * 16 + lm;          // d
            const float bv = bias[n0 + col];
            #pragma unroll
            for (int im = 0; im < 4; ++im) {
                const int row0 = wy * 64 + im * 16 + q * 4;  // s-local
                #pragma unroll
                for (int r = 0; r < 4; ++r)
                    ctile[col * 136 + row0 + r] = f2bf(acc[im][in][r] + bv);
            }
        }
        __syncthreads();
        const int hh = n0 >> 7;
        const int bb = m0 >> 11;
        const int s0 = m0 & (SEQn - 1);
        const int st = (tid & 15) * 8;
        const int d0 = tid >> 4;            // 0..15
        #pragma unroll
        for (int db = 0; db < 8; ++db) {
            const int d = d0 + db * 16;
            const ushort4 v0 = *reinterpret_cast<const ushort4*>(&ctile[d * 136 + st]);
            const ushort4 v1 = *reinterpret_cast<const ushort4*>(&ctile[d * 136 + st + 4]);
            ushort* dstp = Vt + (((size_t)(bb * NHn + hh)) * HDn + d) * SEQn + s0 + st;
            *reinterpret_cast<ushort4*>(dstp)     = v0;
            *reinterpret_cast<ushort4*>(dstp + 4) = v1;
        }
    } else {
        ushort* ctile = smem;                  // 128 rows x stride 136
        #pragma unroll
        for (int in = 0; in < 4; ++in) {
            const int col = wx * 64 + in * 16 + lm;
            const float bv = bias[n0 + col];
            #pragma unroll
            for (int im = 0; im < 4; ++im) {
                const int row0 = wy * 64 + im * 16 + q * 4;
                #pragma unroll
                for (int r = 0; r < 4; ++r)
                    ctile[(row0 + r) * 136 + col] = f2bf(acc[im][in][r] + bv);
            }
        }
        __syncthreads();
        ushort* dst = (sel == 0) ? Qb : Kb;
        const int d = tid & 63;
        const float invf = exp2f(-(float)d * 0.20762050593046f);  // 10000^(-d/64)
        for (int r = tid >> 6; r < 128; r += 4) {
            const int s = (m0 + r) & (SEQn - 1);
            const float ang = (float)s * invf;
            float sn, cs;
            __sincosf(ang, &sn, &cs);
            const float t1 = bf2f(ctile[r * 136 + d]);
            const float t2 = bf2f(ctile[r * 136 + 64 + d]);
            const size_t base = (size_t)(m0 + r) * DMn + n0 + d;
            dst[base]      = f2bf(t1 * cs - t2 * sn);
            dst[base + 64] = f2bf(t1 * sn + t2 * cs);
        }
    }
}

// ---- final GEMM: out(4096x2048 fp32) = AO(bf16) * WT^T + bias (fp32) -------
// 64(M)x128(N) tile; same T4 counted-vmcnt dbuf pipeline (vmcnt(6), 48KB LDS).
__global__ __launch_bounds__(256)
void gemm_out_kernel(const ushort* __restrict__ A, const ushort* __restrict__ BT,
                     const float* __restrict__ bias, float* __restrict__ C)
{
    // slot s: As = smem + s*12288 (64x64), Bs = +4096 (128x64).
    __shared__ __align__(16) ushort smem[24576];   // 48 KB
    const int tid = threadIdx.x;
    const int m0 = blockIdx.y * 64;
    const int n0 = blockIdx.x * 128;
    const int w  = tid >> 6;
    const int l  = tid & 63;
    const int wy = w >> 1, wx = w & 1;
    const int q  = l >> 4, lm = l & 15;
    const int sw = lm & 7;

    f32x4 acc[2][4];
    #pragma unroll
    for (int i = 0; i < 2; ++i)
        #pragma unroll
        for (int j = 0; j < 4; ++j) acc[i][j] = (f32x4)0.0f;

    auto stage = [&](int slot, int kt) {
        ushort* AsS = smem + slot * 12288;
        ushort* BsS = AsS + 4096;
        #pragma unroll
        for (int it = 0; it < 2; ++it) {       // A rows 0..63
            const int v = it * 256 + tid;
            const int r = v >> 3;
            const int cs = ((v & 7) ^ (r & 7)) << 3;
            GLOAD_LDS16(A + (size_t)(m0 + r) * DMn + kt + cs,
                        AsS + (it * 256 + w * 64) * 8);
        }
        #pragma unroll
        for (int it = 0; it < 4; ++it) {       // B rows 0..127
            const int v = it * 256 + tid;
            const int r = v >> 3;
            const int cs = ((v & 7) ^ (r & 7)) << 3;
            GLOAD_LDS16(BT + (size_t)(n0 + r) * DMn + kt + cs,
                        BsS + (it * 256 + w * 64) * 8);
        }
    };

    auto compute = [&](int slot) {
        const ushort* AsS = smem + slot * 12288;
        const ushort* BsS = AsS + 4096;
        #pragma unroll
        for (int ks = 0; ks < 2; ++ks) {
            s16x8 af[2], bfv[4];
            #pragma unroll
            for (int im = 0; im < 2; ++im) {
                const int arow = wy * 32 + im * 16 + lm;
                af[im] = *reinterpret_cast<const s16x8*>(
                    &AsS[arow * 64 + (((ks * 4 + q) ^ sw) << 3)]);
            }
            #pragma unroll
            for (int in = 0; in < 4; ++in) {
                const int brow = wx * 64 + in * 16 + lm;
                bfv[in] = *reinterpret_cast<const s16x8*>(
                    &BsS[brow * 64 + (((ks * 4 + q) ^ sw) << 3)]);
            }
            __builtin_amdgcn_s_setprio(1);
            #pragma unroll
            for (int im = 0; im < 2; ++im)
                #pragma unroll
                for (int in = 0; in < 4; ++in)
                    acc[im][in] = __builtin_amdgcn_mfma_f32_16x16x32_bf16(af[im], bfv[in], acc[im][in], 0, 0, 0);
            __builtin_amdgcn_s_setprio(0);
        }
    };

    const int NT = DMn / 64;   // 32
    stage(0, 0);
    int cur = 0;
    for (int t = 0; t < NT - 1; ++t) {
        stage(cur ^ 1, (t + 1) * 64);
        asm volatile("s_waitcnt vmcnt(6)" ::: "memory");
        __builtin_amdgcn_s_barrier();
        FENCE();
        compute(cur);
        FENCE();
        __builtin_amdgcn_s_barrier();
        FENCE();
        cur ^= 1;
    }
    asm volatile("s_waitcnt vmcnt(0)" ::: "memory");
    __builtin_amdgcn_s_barrier();
    FENCE();
    compute(cur);

    #pragma unroll
    for (int in = 0; in < 4; ++in) {
        const int gcol = n0 + wx * 64 + in * 16 + lm;
        const float bv = bias[gcol];
        #pragma unroll
        for (int im = 0; im < 2; ++im) {
            const int grow0 = m0 + wy * 32 + im * 16 + q * 4;
            #pragma unroll
            for (int r = 0; r < 4; ++r)
                C[(size_t)(grow0 + r) * HIDn + gcol] = acc[im][in][r] + bv;
        }
    }
}

// -------- MFMA flash attention: r4 structure + V-prefetch + T5 setprio ------
// 4 waves/block, one (b,h,16-query tile) per wave. The 8 Vt frag loads are
// hoisted to chunk start (independent of softmax) so their latency overlaps
// QK^T + softmax instead of stalling the PV MFMAs. setprio(1) around MFMA
// clusters (T5: +4-7% on attn, m191 — waves here are phase-desynchronized).
__global__ __launch_bounds__(256)
void attn_mfma_kernel(const ushort* Q, const ushort* __restrict__ K,
                      const ushort* __restrict__ Vt, const float* __restrict__ kw,
                      ushort* AO)
{
    __shared__ ushort plds[4][16 * 40];   // per-wave P tile, stride 40 (2-way = free)
    const int w  = threadIdx.x >> 6;
    const int l  = threadIdx.x & 63;
    const int q  = l >> 4, lm = l & 15;
    const int gw = blockIdx.x * 4 + w;     // b(1) | h(4) | qt(7)
    const int qt = gw & 127;
    const int h  = (gw >> 7) & (NHn - 1);
    const int b  = gw >> 11;
    const int q0 = qt * 16;
    const float f = kw[h] * 0.08838834764831845f;   // kw * HD^-0.5

    s16x8 qf[4];
    const size_t qbase = ((size_t)(b * SEQn + q0 + lm)) * DMn + h * HDn;
    #pragma unroll
    for (int ks = 0; ks < 4; ++ks)
        qf[ks] = *reinterpret_cast<const s16x8*>(Q + qbase + ks * 32 + q * 8);

    f32x4 O[8];
    #pragma unroll
    for (int nt = 0; nt < 8; ++nt) O[nt] = (f32x4)0.0f;
    float m[4]    = {-1e30f, -1e30f, -1e30f, -1e30f};
    float lsum[4] = {0.f, 0.f, 0.f, 0.f};

    const int lo = q0 - WINn;
    const int c0 = lo > 0 ? (lo & ~31) : 0;
    const int nch = (q0 + 16 - c0 + 31) >> 5;

    const size_t kbh = ((size_t)(b * SEQn)) * DMn + h * HDn;
    const size_t vbh = ((size_t)(b * NHn + h)) * HDn * SEQn;

    for (int c = 0; c < nch; ++c) {
        const int kc = c0 + c * 32;
        // ---- prefetch V frags (independent of softmax) ----
        s16x8 vf[8];
        #pragma unroll
        for (int nt = 0; nt < 8; ++nt)
            vf[nt] = *reinterpret_cast<const s16x8*>(
                Vt + vbh + (size_t)(nt * 16 + lm) * SEQn + kc + q * 8);
        // ---- QK^T: two 16-key tiles, 4 chained k-MFMAs each ----
        f32x4 S[2];
        #pragma unroll
        for (int t = 0; t < 2; ++t) {
            f32x4 acc = (f32x4)0.0f;
            const size_t krow = kbh + (size_t)(kc + t * 16 + lm) * DMn;
            s16x8 kf[4];
            #pragma unroll
            for (int ks = 0; ks < 4; ++ks)
                kf[ks] = *reinterpret_cast<const s16x8*>(K + krow + ks * 32 + q * 8);
            __builtin_amdgcn_s_setprio(1);
            #pragma unroll
            for (int ks = 0; ks < 4; ++ks)
                acc = __builtin_amdgcn_mfma_f32_16x16x32_bf16(qf[ks], kf[ks], acc, 0, 0, 0);
            __builtin_amdgcn_s_setprio(0);
            S[t] = acc;
        }
        // ---- scale, mask, online softmax ----
        const int j0 = kc + lm, j1 = kc + 16 + lm;
        #pragma unroll
        for (int r = 0; r < 4; ++r) {
            const int i = q0 + q * 4 + r;
            float v0 = S[0][r] * f;
            float v1 = S[1][r] * f;
            if (j0 > i || j0 < i - WINn) v0 = -1e30f;
            if (j1 > i || j1 < i - WINn) v1 = -1e30f;
            float mx = fmaxf(v0, v1);
            #pragma unroll
            for (int off = 8; off > 0; off >>= 1)
                mx = fmaxf(mx, __shfl_xor(mx, off));
            const float mn = fmaxf(m[r], mx);
            const float alpha = __expf(m[r] - mn);
            m[r] = mn;
            const ushort h0 = f2bf(__expf(v0 - mn));
            const ushort h1 = f2bf(__expf(v1 - mn));
            plds[w][(q * 4 + r) * 40 + lm]      = h0;
            plds[w][(q * 4 + r) * 40 + 16 + lm] = h1;
            float ps = bf2f(h0) + bf2f(h1);
            #pragma unroll
            for (int off = 8; off > 0; off >>= 1)
                ps += __shfl_xor(ps, off);
            lsum[r] = lsum[r] * alpha + ps;
            #pragma unroll
            for (int nt = 0; nt < 8; ++nt) O[nt][r] *= alpha;
        }
        // ---- P -> A-frag via per-wave LDS round trip; P·V ----
        const s16x8 pf = *reinterpret_cast<const s16x8*>(&plds[w][lm * 40 + q * 8]);
        __builtin_amdgcn_s_setprio(1);
        #pragma unroll
        for (int nt = 0; nt < 8; ++nt)
            O[nt] = __builtin_amdgcn_mfma_f32_16x16x32_bf16(pf, vf[nt], O[nt], 0, 0, 0);
        __builtin_amdgcn_s_setprio(0);
    }
    #pragma unroll
    for (int r = 0; r < 4; ++r) {
        const float inv = 1.0f / lsum[r];
        const size_t orow = ((size_t)(b * SEQn + q0 + q * 4 + r)) * DMn + h * HDn;
        #pragma unroll
        for (int nt = 0; nt < 8; ++nt)
            AO[orow + nt * 16 + lm] = f2bf(O[nt][r] * inv);
    }
}

extern "C" void kernel_launch(void* const* d_in, const int* in_sizes, int n_in,
                              void* d_out, int out_size, void* d_ws, size_t ws_size,
                              hipStream_t stream)
{
    (void)in_sizes; (void)n_in; (void)out_size;
    const float* x  = (const float*)d_in[0];
    const float* WQ = (const float*)d_in[1];
    const float* bQ = (const float*)d_in[2];
    const float* WK = (const float*)d_in[3];
    const float* bK = (const float*)d_in[4];
    const float* WV = (const float*)d_in[5];
    const float* bV = (const float*)d_in[6];
    const float* WO = (const float*)d_in[7];
    const float* bO = (const float*)d_in[8];
    const float* kw = (const float*)d_in[9];
    float* out = (float*)d_out;

    // Full path: Qb/Kb/Vt (48 MB) + WT 4 slabs (32 MB) + xb (16 MB) = 96 MB.
    // Fallback (ws < 96 MB): 3 slabs, fp32-A QKV GEMM, late WO transpose.
    char* ws = (char*)d_ws;
    const size_t AELEMS = (size_t)MROWS * DMn;         // 4096*2048
    ushort* Qb = (ushort*)ws;                          // also AO (in-place)
    ushort* Kb = (ushort*)(ws + AELEMS * 2);
    ushort* Vt = (ushort*)(ws + AELEMS * 4);           // [b][h][d][s]
    ushort* WT = (ushort*)(ws + AELEMS * 6);           // up to 4 x 2048x2048 bf16
    const size_t FULL = AELEMS * 6 + WELEMS * 8 + AELEMS * 2;   // 96 MB
    const bool have_full = ws_size >= FULL;
    ushort* xb = (ushort*)(ws + AELEMS * 6 + WELEMS * 8);

    const dim3 tblk(32, 8);

    if (have_full) {
        transpose_all_kernel<<<dim3(64, 64, 5), tblk, 0, stream>>>(WQ, WK, WV, WO, WT, x, xb);
        gemm_qkv_kernel<1><<<dim3(3 * DMn / 128, MROWS / 128), 256, 0, stream>>>(
            xb, WT, bQ, bK, bV, Qb, Kb, Vt);
        attn_mfma_kernel<<<dim3(BATCHn * NHn * (SEQn / 16) / 4), 256, 0, stream>>>(Qb, Kb, Vt, kw, Qb);
        gemm_out_kernel<<<dim3(HIDn / 128, MROWS / 64), 256, 0, stream>>>(
            Qb, WT + 3 * WELEMS, bO, out);
    } else {
        transpose_all_kernel<<<dim3(64, 64, 3), tblk, 0, stream>>>(WQ, WK, WV, WO, WT, x, xb);
        gemm_qkv_kernel<0><<<dim3(3 * DMn / 128, MROWS / 128), 256, 0, stream>>>(
            x, WT, bQ, bK, bV, Qb, Kb, Vt);
        attn_mfma_kernel<<<dim3(BATCHn * NHn * (SEQn / 16) / 4), 256, 0, stream>>>(Qb, Kb, Vt, kw, Qb);
        transpose_cvt_kernel<<<dim3(64, 64), tblk, 0, stream>>>(WO, WT);
        gemm_out_kernel<<<dim3(HIDn / 128, MROWS / 64), 256, 0, stream>>>(Qb, WT, bO, out);
    }
}